// Round 2
// baseline (385.495 us; speedup 1.0000x reference)
//
#include <hip/hip_runtime.h>

typedef unsigned short u16;
typedef u16 u16x8 __attribute__((ext_vector_type(8)));
typedef u16 u16x4 __attribute__((ext_vector_type(4)));
typedef __bf16 bf16x8 __attribute__((ext_vector_type(8)));
typedef float f32x4 __attribute__((ext_vector_type(4)));

#define DEVI static __device__ __forceinline__

#define BB 32
#define NN 577
#define CC 1024
#define HH 16
#define DD 64
#define MM (BB * NN)   // 18464
#define SCALE_ 0.125f

DEVI u16 f2bf(float f) {
  union { float f; unsigned u; } v; v.f = f;
  unsigned r = v.u + 0x7FFFu + ((v.u >> 16) & 1u);
  return (u16)(r >> 16);
}
DEVI float bf2f(u16 b) {
  union { unsigned u; float f; } v; v.u = ((unsigned)b) << 16; return v.f;
}
DEVI f32x4 mfma16(u16x8 a, u16x8 b, f32x4 c) {
  return __builtin_amdgcn_mfma_f32_16x16x32_bf16(
      __builtin_bit_cast(bf16x8, a), __builtin_bit_cast(bf16x8, b), c, 0, 0, 0);
}
DEVI void gload_lds16(const u16* g, u16* l) {
  __builtin_amdgcn_global_load_lds(
      (const __attribute__((address_space(1))) void*)g,
      (__attribute__((address_space(3))) void*)l, 16, 0, 0);
}

// ---------------- fp32 -> bf16 convert ----------------
__global__ void cvt_kernel(const float* __restrict__ in, u16* __restrict__ out, int n4) {
  int i = blockIdx.x * blockDim.x + threadIdx.x;
  int stride = gridDim.x * blockDim.x;
  for (; i < n4; i += stride) {
    float4 v = ((const float4*)in)[i];
    u16x4 o = { f2bf(v.x), f2bf(v.y), f2bf(v.z), f2bf(v.w) };
    ((u16x4*)out)[i] = o;
  }
}

// ---------------- GEMM (m97 structure): C[M,N] = A[M,K] * Bw[N,K]^T (+bias) ----
// global_load_lds width-16 staging into linear LDS [128][64], 2-barrier K-loop.
__global__ __launch_bounds__(256) void gemm_bt2(
    const u16* __restrict__ A, const u16* __restrict__ Bw,
    u16* __restrict__ Cb, float* __restrict__ Cf, const float* __restrict__ bias,
    int M, int N, int K, int MT, int NT)
{
  __shared__ u16 Als[128 * 64];
  __shared__ u16 Bls[128 * 64];

  // bijective XCD swizzle (m204), nt-fastest within an XCD's chunk
  int nwg = MT * NT;
  int orig = blockIdx.x;
  int q = nwg >> 3, r = nwg & 7;
  int xcd = orig & 7, idx = orig >> 3;
  int wg = (xcd < r ? xcd * (q + 1) : r * (q + 1) + (xcd - r) * q) + idx;
  int mt = wg / NT, nt = wg % NT;

  const int t = threadIdx.x, lane = t & 63, w = t >> 6;
  const int wr = (w >> 1) * 64, wc = (w & 1) * 64;
  const int fr = lane & 15, fg = lane >> 4;
  const int m0 = mt * 128, n0 = nt * 128;
  f32x4 acc[4][4] = {};

  // per-lane global staging addresses: wave w stages chunks w*4+i (i=0..3),
  // chunk c covers rows c*8+(lane>>3), col (lane&7)*8 of the 128x64 tile.
  const u16* pA[4];
  const u16* pB[4];
#pragma unroll
  for (int i = 0; i < 4; ++i) {
    int row = w * 32 + i * 8 + (lane >> 3);
    int ga = m0 + row; if (ga > M - 1) ga = M - 1;
    pA[i] = A + (size_t)ga * K + (lane & 7) * 8;
    pB[i] = Bw + (size_t)(n0 + row) * K + (lane & 7) * 8;
  }

  for (int kt = 0; kt < K; kt += 64) {
#pragma unroll
    for (int i = 0; i < 4; ++i) {
      int c = w * 4 + i;
      gload_lds16(pA[i] + kt, &Als[c * 512]);
      gload_lds16(pB[i] + kt, &Bls[c * 512]);
    }
    __syncthreads();   // drains vmcnt + barrier
#pragma unroll
    for (int kk = 0; kk < 2; ++kk) {
      u16x8 af[4], bfr[4];
#pragma unroll
      for (int m = 0; m < 4; ++m)
        af[m] = *(const u16x8*)&Als[(wr + m * 16 + fr) * 64 + kk * 32 + fg * 8];
#pragma unroll
      for (int n = 0; n < 4; ++n)
        bfr[n] = *(const u16x8*)&Bls[(wc + n * 16 + fr) * 64 + kk * 32 + fg * 8];
#pragma unroll
      for (int m = 0; m < 4; ++m)
#pragma unroll
        for (int n = 0; n < 4; ++n)
          acc[m][n] = mfma16(af[m], bfr[n], acc[m][n]);
    }
    __syncthreads();
  }

#pragma unroll
  for (int m = 0; m < 4; ++m) {
#pragma unroll
    for (int j = 0; j < 4; ++j) {
      int row = m0 + wr + m * 16 + fg * 4 + j;
      if (row >= M) continue;
#pragma unroll
      for (int n = 0; n < 4; ++n) {
        int col = n0 + wc + n * 16 + fr;
        float v = acc[m][n][j];
        if (Cf) Cf[(size_t)row * N + col] = v + bias[col];
        else    Cb[(size_t)row * N + col] = f2bf(v);
      }
    }
  }
}

// ---------------- 3x3 avg pool of Xq (24x24 -> 8x8) ----------------
__global__ __launch_bounds__(256) void pool_kernel(const u16* __restrict__ qkv, u16* __restrict__ Qp) {
  int b = blockIdx.x >> 6, pq = blockIdx.x & 63;
  int py = pq >> 3, px = pq & 7;
  int c0 = threadIdx.x * 4;
  float s0 = 0.f, s1 = 0.f, s2 = 0.f, s3 = 0.f;
#pragma unroll
  for (int dy = 0; dy < 3; ++dy)
#pragma unroll
    for (int dx = 0; dx < 3; ++dx) {
      int n = (py * 3 + dy) * 24 + px * 3 + dx;
      u16x4 v = *(const u16x4*)(qkv + (size_t)(b * NN + n) * 3072 + c0);
      s0 += bf2f(v[0]); s1 += bf2f(v[1]); s2 += bf2f(v[2]); s3 += bf2f(v[3]);
    }
  const float r = 1.f / 9.f;
  u16x4 o = { f2bf(s0 * r), f2bf(s1 * r), f2bf(s2 * r), f2bf(s3 * r) };
  *(u16x4*)(Qp + (size_t)(b * 64 + pq) * CC + c0) = o;
}

// ---------------- Stage 1: pooled Q (64) attends to K/V (577) ----------------
// One block per (b,h). Output: Q_delta TRANSPOSED: QdT[bh][dv][q], bf16.
__global__ __launch_bounds__(256) void stage1_kernel(
    const u16* __restrict__ qkv, const u16* __restrict__ Qp, u16* __restrict__ QdT)
{
  __shared__ u16 Kls[64][72];
  __shared__ u16 Vt[64][72];     // Vt[dv][key]
  __shared__ u16 Pls[4][16][72];
  int bh = blockIdx.x, b = bh >> 4, h = bh & 15;
  int t = threadIdx.x, lane = t & 63, w = t >> 6;
  int fr = lane & 15, fg = lane >> 4;

  const u16* Qb = Qp + (size_t)(b * 64 + w * 16 + fr) * CC + h * DD;
  u16x8 qf0 = *(const u16x8*)(Qb + fg * 8);
  u16x8 qf1 = *(const u16x8*)(Qb + 32 + fg * 8);

  f32x4 o[4] = {};
  float rowm[4] = {-1e30f, -1e30f, -1e30f, -1e30f};
  float rowl[4] = {};

  for (int kt = 0; kt < 10; ++kt) {
#pragma unroll
    for (int i = 0; i < 2; ++i) {
      int g = t + i * 256;
      int key = g >> 3, cc = (g & 7) * 8;
      int n = kt * 64 + key;
      u16x8 kv = {}, vv = {};
      if (n < NN) {
        const u16* p = qkv + (size_t)(b * NN + n) * 3072 + h * DD + cc;
        kv = *(const u16x8*)(p + CC);
        vv = *(const u16x8*)(p + 2 * CC);
      }
      *(u16x8*)&Kls[key][cc] = kv;
#pragma unroll
      for (int j = 0; j < 8; ++j) Vt[cc + j][key] = vv[j];
    }
    __syncthreads();

    f32x4 s[4] = {};
#pragma unroll
    for (int kk = 0; kk < 2; ++kk) {
      u16x8 qf = kk ? qf1 : qf0;
#pragma unroll
      for (int n = 0; n < 4; ++n) {
        u16x8 kf = *(const u16x8*)&Kls[n * 16 + fr][kk * 32 + fg * 8];
        s[n] = mfma16(qf, kf, s[n]);
      }
    }
    float mx[4] = {-1e30f, -1e30f, -1e30f, -1e30f};
#pragma unroll
    for (int n = 0; n < 4; ++n) {
      int key = kt * 64 + n * 16 + fr;
#pragma unroll
      for (int j = 0; j < 4; ++j) {
        float v = s[n][j] * SCALE_;
        if (key >= NN) v = -1e30f;
        s[n][j] = v;
        mx[j] = fmaxf(mx[j], v);
      }
    }
    for (int d = 1; d < 16; d <<= 1) {
#pragma unroll
      for (int j = 0; j < 4; ++j) mx[j] = fmaxf(mx[j], __shfl_xor(mx[j], d));
    }
    float corr[4];
#pragma unroll
    for (int j = 0; j < 4; ++j) {
      float mn = fmaxf(rowm[j], mx[j]);
      corr[j] = __expf(rowm[j] - mn);
      rowm[j] = mn;
    }
    float rs[4] = {};
#pragma unroll
    for (int n = 0; n < 4; ++n)
#pragma unroll
      for (int j = 0; j < 4; ++j) {
        float p = __expf(s[n][j] - rowm[j]);
        s[n][j] = p;
        rs[j] += p;
      }
    for (int d = 1; d < 16; d <<= 1) {
#pragma unroll
      for (int j = 0; j < 4; ++j) rs[j] += __shfl_xor(rs[j], d);
    }
#pragma unroll
    for (int j = 0; j < 4; ++j) rowl[j] = rowl[j] * corr[j] + rs[j];
#pragma unroll
    for (int n = 0; n < 4; ++n)
#pragma unroll
      for (int j = 0; j < 4; ++j) o[n][j] *= corr[j];

#pragma unroll
    for (int n = 0; n < 4; ++n)
#pragma unroll
      for (int j = 0; j < 4; ++j)
        Pls[w][fg * 4 + j][n * 16 + fr] = f2bf(s[n][j]);
    __syncthreads();

#pragma unroll
    for (int kk = 0; kk < 2; ++kk) {
      u16x8 pf = *(const u16x8*)&Pls[w][fr][kk * 32 + fg * 8];
#pragma unroll
      for (int n = 0; n < 4; ++n) {
        u16x8 vf = *(const u16x8*)&Vt[n * 16 + fr][kk * 32 + fg * 8];
        o[n] = mfma16(pf, vf, o[n]);
      }
    }
    __syncthreads();
  }

#pragma unroll
  for (int n = 0; n < 4; ++n)
#pragma unroll
    for (int j = 0; j < 4; ++j) {
      int dv = n * 16 + fr, q2 = w * 16 + fg * 4 + j;
      QdT[((size_t)bh * 64 + dv) * 64 + q2] = f2bf(o[n][j] / rowl[j]);
    }
}

// ---------------- Stage 2 ----------------
__global__ __launch_bounds__(256) void stage2_kernel(
    const u16* __restrict__ qkv, const u16* __restrict__ Qp,
    const u16* __restrict__ QdT, u16* __restrict__ AO)
{
  __shared__ u16 Qpl[64][72];
  __shared__ u16 Qdl[64][72];
  __shared__ u16 Pls[4][16][72];
  int id = blockIdx.x;
  int ntile = id % 10;
  int bh = id / 10, b = bh >> 4, h = bh & 15;
  int t = threadIdx.x, lane = t & 63, w = t >> 6;
  int fr = lane & 15, fg = lane >> 4;

#pragma unroll
  for (int i = 0; i < 2; ++i) {
    int g = t + i * 256;
    int row = g >> 3, cc = (g & 7) * 8;
    *(u16x8*)&Qpl[row][cc] = *(const u16x8*)(Qp + (size_t)(b * 64 + row) * CC + h * DD + cc);
    *(u16x8*)&Qdl[row][cc] = *(const u16x8*)(QdT + ((size_t)bh * 64 + row) * 64 + cc);
  }
  __syncthreads();

  int n0 = ntile * 64;
  int qrow = n0 + w * 16 + fr;
  int qc = qrow < NN ? qrow : NN - 1;
  const u16* Qb = qkv + (size_t)(b * NN + qc) * 3072 + h * DD;
  u16x8 qf0 = *(const u16x8*)(Qb + fg * 8);
  u16x8 qf1 = *(const u16x8*)(Qb + 32 + fg * 8);

  f32x4 s[4] = {};
#pragma unroll
  for (int kk = 0; kk < 2; ++kk) {
    u16x8 qf = kk ? qf1 : qf0;
#pragma unroll
    for (int n = 0; n < 4; ++n) {
      u16x8 bfrag = *(const u16x8*)&Qpl[n * 16 + fr][kk * 32 + fg * 8];
      s[n] = mfma16(qf, bfrag, s[n]);
    }
  }
  float mx[4] = {-1e30f, -1e30f, -1e30f, -1e30f};
#pragma unroll
  for (int n = 0; n < 4; ++n)
#pragma unroll
    for (int j = 0; j < 4; ++j) {
      float v = s[n][j] * SCALE_;
      s[n][j] = v;
      mx[j] = fmaxf(mx[j], v);
    }
  for (int d = 1; d < 16; d <<= 1) {
#pragma unroll
    for (int j = 0; j < 4; ++j) mx[j] = fmaxf(mx[j], __shfl_xor(mx[j], d));
  }
  float rs[4] = {};
#pragma unroll
  for (int n = 0; n < 4; ++n)
#pragma unroll
    for (int j = 0; j < 4; ++j) {
      float p = __expf(s[n][j] - mx[j]);
      s[n][j] = p;
      rs[j] += p;
    }
  for (int d = 1; d < 16; d <<= 1) {
#pragma unroll
    for (int j = 0; j < 4; ++j) rs[j] += __shfl_xor(rs[j], d);
  }

#pragma unroll
  for (int n = 0; n < 4; ++n)
#pragma unroll
    for (int j = 0; j < 4; ++j)
      Pls[w][fg * 4 + j][n * 16 + fr] = f2bf(s[n][j]);
  __syncthreads();

  f32x4 of[4] = {};
#pragma unroll
  for (int kk = 0; kk < 2; ++kk) {
    u16x8 pf = *(const u16x8*)&Pls[w][fr][kk * 32 + fg * 8];
#pragma unroll
    for (int n = 0; n < 4; ++n) {
      u16x8 qd = *(const u16x8*)&Qdl[n * 16 + fr][kk * 32 + fg * 8];
      of[n] = mfma16(pf, qd, of[n]);
    }
  }

#pragma unroll
  for (int n = 0; n < 4; ++n)
#pragma unroll
    for (int j = 0; j < 4; ++j) {
      int orow = n0 + w * 16 + fg * 4 + j;
      if (orow < NN)
        AO[(size_t)(b * NN + orow) * CC + h * DD + n * 16 + fr] = f2bf(of[n][j] / rs[j]);
    }
}

// ---------------- launch ----------------
extern "C" void kernel_launch(void* const* d_in, const int* in_sizes, int n_in,
                              void* d_out, int out_size, void* d_ws, size_t ws_size,
                              hipStream_t stream) {
  const float* X     = (const float*)d_in[0];
  const float* Wqkv  = (const float*)d_in[1];
  const float* Wproj = (const float*)d_in[2];
  const float* bproj = (const float*)d_in[3];

  char* ws = (char*)d_ws;
  u16* Xb  = (u16*)(ws + 0);            // 18464*1024*2 = 37,814,272
  u16* Wqb = (u16*)(ws + 37814272);     // 3072*1024*2  =  6,291,456
  u16* Wpb = (u16*)(ws + 44105728);     // 1024*1024*2  =  2,097,152
  u16* qkv = (u16*)(ws + 46202880);     // 18464*3072*2 = 113,442,816
  u16* Qpb = (u16*)(ws + 159645696);    // 32*64*1024*2 =  4,194,304
  u16* QdT = (u16*)(ws + 163840000);    // 512*64*64*2  =  4,194,304
  u16* AO  = (u16*)(ws + 168034304);    // 18464*1024*2 = 37,814,272

  cvt_kernel<<<2048, 256, 0, stream>>>(X, Xb, (BB * NN * CC) / 4);
  cvt_kernel<<<1024, 256, 0, stream>>>(Wqkv, Wqb, (3 * CC * CC) / 4);
  cvt_kernel<<<512, 256, 0, stream>>>(Wproj, Wpb, (CC * CC) / 4);

  gemm_bt2<<<145 * 24, 256, 0, stream>>>(Xb, Wqb, qkv, nullptr, nullptr,
                                         MM, 3 * CC, CC, 145, 24);

  pool_kernel<<<BB * 64, 256, 0, stream>>>(qkv, Qpb);
  stage1_kernel<<<BB * HH, 256, 0, stream>>>(qkv, Qpb, QdT);
  stage2_kernel<<<BB * HH * 10, 256, 0, stream>>>(qkv, Qpb, QdT, AO);

  gemm_bt2<<<145 * 8, 256, 0, stream>>>(AO, Wpb, nullptr, (float*)d_out, bproj,
                                        MM, CC, CC, 145, 8);
}

// Round 3
// 302.185 us; speedup vs baseline: 1.2757x; 1.2757x over previous
//
#include <hip/hip_runtime.h>

typedef unsigned short u16;
typedef u16 u16x8 __attribute__((ext_vector_type(8)));
typedef u16 u16x4 __attribute__((ext_vector_type(4)));
typedef __bf16 bf16x8 __attribute__((ext_vector_type(8)));
typedef float f32x4 __attribute__((ext_vector_type(4)));

#define DEVI static __device__ __forceinline__

#define BB 32
#define NN 577
#define CC 1024
#define HH 16
#define DD 64
#define MM (BB * NN)   // 18464
#define SCALE_ 0.125f

DEVI u16 f2bf(float f) {
  union { float f; unsigned u; } v; v.f = f;
  unsigned r = v.u + 0x7FFFu + ((v.u >> 16) & 1u);
  return (u16)(r >> 16);
}
DEVI float bf2f(u16 b) {
  union { unsigned u; float f; } v; v.u = ((unsigned)b) << 16; return v.f;
}
DEVI f32x4 mfma16(u16x8 a, u16x8 b, f32x4 c) {
  return __builtin_amdgcn_mfma_f32_16x16x32_bf16(
      __builtin_bit_cast(bf16x8, a), __builtin_bit_cast(bf16x8, b), c, 0, 0, 0);
}
DEVI void gload_lds16(const u16* g, u16* l) {
  __builtin_amdgcn_global_load_lds(
      (const __attribute__((address_space(1))) void*)g,
      (__attribute__((address_space(3))) void*)l, 16, 0, 0);
}

// ---------------- fp32 -> bf16 convert ----------------
__global__ void cvt_kernel(const float* __restrict__ in, u16* __restrict__ out, int n4) {
  int i = blockIdx.x * blockDim.x + threadIdx.x;
  int stride = gridDim.x * blockDim.x;
  for (; i < n4; i += stride) {
    float4 v = ((const float4*)in)[i];
    u16x4 o = { f2bf(v.x), f2bf(v.y), f2bf(v.z), f2bf(v.w) };
    ((u16x4*)out)[i] = o;
  }
}

// ---------------- GEMM (m97 structure + T2 swizzle): C = A * Bw^T (+bias) ----
// global_load_lds width-16 into linear LDS [128][64]; the LDS *logical* layout
// is XOR-swizzled (16B chunk col ^= row&7) by pre-swizzling the per-lane
// GLOBAL source column (rule #21: linear dest + inv-swz source + swz read).
__global__ __launch_bounds__(256) void gemm_bt2(
    const u16* __restrict__ A, const u16* __restrict__ Bw,
    u16* __restrict__ Cb, float* __restrict__ Cf, const float* __restrict__ bias,
    int M, int N, int K, int MT, int NT)
{
  __shared__ u16 Als[128 * 64];
  __shared__ u16 Bls[128 * 64];

  // bijective XCD swizzle (m204), nt-fastest within an XCD's chunk
  int nwg = MT * NT;
  int orig = blockIdx.x;
  int q = nwg >> 3, r = nwg & 7;
  int xcd = orig & 7, idx = orig >> 3;
  int wg = (xcd < r ? xcd * (q + 1) : r * (q + 1) + (xcd - r) * q) + idx;
  int mt = wg / NT, nt = wg % NT;

  const int t = threadIdx.x, lane = t & 63, w = t >> 6;
  const int wr = (w >> 1) * 64, wc = (w & 1) * 64;
  const int fr = lane & 15, fg = lane >> 4;
  const int m0 = mt * 128, n0 = nt * 128;
  f32x4 acc[4][4] = {};

  // staging: wave w stages chunks w*4+i; chunk c = rows [c*8, c*8+8) of the
  // 128x64 tile. lane l writes LDS linear slot row=c*8+(l>>3), chunkcol=(l&7);
  // source column is XOR-swizzled so LDS[row][cc] = global[row][cc ^ (row&7)].
  const int swcol = ((lane & 7) ^ ((lane >> 3) & 7)) * 8;
  const u16* pA[4];
  const u16* pB[4];
#pragma unroll
  for (int i = 0; i < 4; ++i) {
    int row = w * 32 + i * 8 + (lane >> 3);
    int ga = m0 + row; if (ga > M - 1) ga = M - 1;
    pA[i] = A + (size_t)ga * K + swcol;
    pB[i] = Bw + (size_t)(n0 + row) * K + swcol;
  }

  for (int kt = 0; kt < K; kt += 64) {
#pragma unroll
    for (int i = 0; i < 4; ++i) {
      int c = w * 4 + i;
      gload_lds16(pA[i] + kt, &Als[c * 512]);
      gload_lds16(pB[i] + kt, &Bls[c * 512]);
    }
    __syncthreads();   // drains vmcnt + barrier
#pragma unroll
    for (int kk = 0; kk < 2; ++kk) {
      u16x8 af[4], bfr[4];
#pragma unroll
      for (int m = 0; m < 4; ++m) {
        int row = wr + m * 16 + fr;
        int ch = (kk * 4 + fg) ^ (fr & 7);           // swizzled 16B-chunk col
        af[m] = *(const u16x8*)&Als[row * 64 + ch * 8];
      }
#pragma unroll
      for (int n = 0; n < 4; ++n) {
        int row = wc + n * 16 + fr;
        int ch = (kk * 4 + fg) ^ (fr & 7);
        bfr[n] = *(const u16x8*)&Bls[row * 64 + ch * 8];
      }
#pragma unroll
      for (int m = 0; m < 4; ++m)
#pragma unroll
        for (int n = 0; n < 4; ++n)
          acc[m][n] = mfma16(af[m], bfr[n], acc[m][n]);
    }
    __syncthreads();
  }

#pragma unroll
  for (int m = 0; m < 4; ++m) {
#pragma unroll
    for (int j = 0; j < 4; ++j) {
      int row = m0 + wr + m * 16 + fg * 4 + j;
      if (row >= M) continue;
#pragma unroll
      for (int n = 0; n < 4; ++n) {
        int col = n0 + wc + n * 16 + fr;
        float v = acc[m][n][j];
        if (Cf) Cf[(size_t)row * N + col] = v + bias[col];
        else    Cb[(size_t)row * N + col] = f2bf(v);
      }
    }
  }
}

// ---------------- 3x3 avg pool of Xq (24x24 -> 8x8) ----------------
__global__ __launch_bounds__(256) void pool_kernel(const u16* __restrict__ qkv, u16* __restrict__ Qp) {
  int b = blockIdx.x >> 6, pq = blockIdx.x & 63;
  int py = pq >> 3, px = pq & 7;
  int c0 = threadIdx.x * 4;
  float s0 = 0.f, s1 = 0.f, s2 = 0.f, s3 = 0.f;
#pragma unroll
  for (int dy = 0; dy < 3; ++dy)
#pragma unroll
    for (int dx = 0; dx < 3; ++dx) {
      int n = (py * 3 + dy) * 24 + px * 3 + dx;
      u16x4 v = *(const u16x4*)(qkv + (size_t)(b * NN + n) * 3072 + c0);
      s0 += bf2f(v[0]); s1 += bf2f(v[1]); s2 += bf2f(v[2]); s3 += bf2f(v[3]);
    }
  const float r = 1.f / 9.f;
  u16x4 o = { f2bf(s0 * r), f2bf(s1 * r), f2bf(s2 * r), f2bf(s3 * r) };
  *(u16x4*)(Qp + (size_t)(b * 64 + pq) * CC + c0) = o;
}

// ---------------- Stage 1: pooled Q (64) attends to K/V (577) ----------------
__global__ __launch_bounds__(256) void stage1_kernel(
    const u16* __restrict__ qkv, const u16* __restrict__ Qp, u16* __restrict__ QdT)
{
  __shared__ u16 Kls[64][72];
  __shared__ u16 Vt[64][72];     // Vt[dv][key]
  __shared__ u16 Pls[4][16][72];
  int bh = blockIdx.x, b = bh >> 4, h = bh & 15;
  int t = threadIdx.x, lane = t & 63, w = t >> 6;
  int fr = lane & 15, fg = lane >> 4;

  const u16* Qb = Qp + (size_t)(b * 64 + w * 16 + fr) * CC + h * DD;
  u16x8 qf0 = *(const u16x8*)(Qb + fg * 8);
  u16x8 qf1 = *(const u16x8*)(Qb + 32 + fg * 8);

  f32x4 o[4] = {};
  float rowm[4] = {-1e30f, -1e30f, -1e30f, -1e30f};
  float rowl[4] = {};

  for (int kt = 0; kt < 10; ++kt) {
#pragma unroll
    for (int i = 0; i < 2; ++i) {
      int g = t + i * 256;
      int key = g >> 3, cc = (g & 7) * 8;
      int n = kt * 64 + key;
      u16x8 kv = {}, vv = {};
      if (n < NN) {
        const u16* p = qkv + (size_t)(b * NN + n) * 3072 + h * DD + cc;
        kv = *(const u16x8*)(p + CC);
        vv = *(const u16x8*)(p + 2 * CC);
      }
      *(u16x8*)&Kls[key][cc] = kv;
#pragma unroll
      for (int j = 0; j < 8; ++j) Vt[cc + j][key] = vv[j];
    }
    __syncthreads();

    f32x4 s[4] = {};
#pragma unroll
    for (int kk = 0; kk < 2; ++kk) {
      u16x8 qf = kk ? qf1 : qf0;
#pragma unroll
      for (int n = 0; n < 4; ++n) {
        u16x8 kf = *(const u16x8*)&Kls[n * 16 + fr][kk * 32 + fg * 8];
        s[n] = mfma16(qf, kf, s[n]);
      }
    }
    float mx[4] = {-1e30f, -1e30f, -1e30f, -1e30f};
#pragma unroll
    for (int n = 0; n < 4; ++n) {
      int key = kt * 64 + n * 16 + fr;
#pragma unroll
      for (int j = 0; j < 4; ++j) {
        float v = s[n][j] * SCALE_;
        if (key >= NN) v = -1e30f;
        s[n][j] = v;
        mx[j] = fmaxf(mx[j], v);
      }
    }
    for (int d = 1; d < 16; d <<= 1) {
#pragma unroll
      for (int j = 0; j < 4; ++j) mx[j] = fmaxf(mx[j], __shfl_xor(mx[j], d));
    }
    float corr[4];
#pragma unroll
    for (int j = 0; j < 4; ++j) {
      float mn = fmaxf(rowm[j], mx[j]);
      corr[j] = __expf(rowm[j] - mn);
      rowm[j] = mn;
    }
    float rs[4] = {};
#pragma unroll
    for (int n = 0; n < 4; ++n)
#pragma unroll
      for (int j = 0; j < 4; ++j) {
        float p = __expf(s[n][j] - rowm[j]);
        s[n][j] = p;
        rs[j] += p;
      }
    for (int d = 1; d < 16; d <<= 1) {
#pragma unroll
      for (int j = 0; j < 4; ++j) rs[j] += __shfl_xor(rs[j], d);
    }
#pragma unroll
    for (int j = 0; j < 4; ++j) rowl[j] = rowl[j] * corr[j] + rs[j];
#pragma unroll
    for (int n = 0; n < 4; ++n)
#pragma unroll
      for (int j = 0; j < 4; ++j) o[n][j] *= corr[j];

#pragma unroll
    for (int n = 0; n < 4; ++n)
#pragma unroll
      for (int j = 0; j < 4; ++j)
        Pls[w][fg * 4 + j][n * 16 + fr] = f2bf(s[n][j]);
    __syncthreads();

#pragma unroll
    for (int kk = 0; kk < 2; ++kk) {
      u16x8 pf = *(const u16x8*)&Pls[w][fr][kk * 32 + fg * 8];
#pragma unroll
      for (int n = 0; n < 4; ++n) {
        u16x8 vf = *(const u16x8*)&Vt[n * 16 + fr][kk * 32 + fg * 8];
        o[n] = mfma16(pf, vf, o[n]);
      }
    }
    __syncthreads();
  }

#pragma unroll
  for (int n = 0; n < 4; ++n)
#pragma unroll
    for (int j = 0; j < 4; ++j) {
      int dv = n * 16 + fr, q2 = w * 16 + fg * 4 + j;
      QdT[((size_t)bh * 64 + dv) * 64 + q2] = f2bf(o[n][j] / rowl[j]);
    }
}

// ---------------- Stage 2 ----------------
__global__ __launch_bounds__(256) void stage2_kernel(
    const u16* __restrict__ qkv, const u16* __restrict__ Qp,
    const u16* __restrict__ QdT, u16* __restrict__ AO)
{
  __shared__ u16 Qpl[64][72];
  __shared__ u16 Qdl[64][72];
  __shared__ u16 Pls[4][16][72];
  int id = blockIdx.x;
  int ntile = id % 10;
  int bh = id / 10, b = bh >> 4, h = bh & 15;
  int t = threadIdx.x, lane = t & 63, w = t >> 6;
  int fr = lane & 15, fg = lane >> 4;

#pragma unroll
  for (int i = 0; i < 2; ++i) {
    int g = t + i * 256;
    int row = g >> 3, cc = (g & 7) * 8;
    *(u16x8*)&Qpl[row][cc] = *(const u16x8*)(Qp + (size_t)(b * 64 + row) * CC + h * DD + cc);
    *(u16x8*)&Qdl[row][cc] = *(const u16x8*)(QdT + ((size_t)bh * 64 + row) * 64 + cc);
  }
  __syncthreads();

  int n0 = ntile * 64;
  int qrow = n0 + w * 16 + fr;
  int qc = qrow < NN ? qrow : NN - 1;
  const u16* Qb = qkv + (size_t)(b * NN + qc) * 3072 + h * DD;
  u16x8 qf0 = *(const u16x8*)(Qb + fg * 8);
  u16x8 qf1 = *(const u16x8*)(Qb + 32 + fg * 8);

  f32x4 s[4] = {};
#pragma unroll
  for (int kk = 0; kk < 2; ++kk) {
    u16x8 qf = kk ? qf1 : qf0;
#pragma unroll
    for (int n = 0; n < 4; ++n) {
      u16x8 bfrag = *(const u16x8*)&Qpl[n * 16 + fr][kk * 32 + fg * 8];
      s[n] = mfma16(qf, bfrag, s[n]);
    }
  }
  float mx[4] = {-1e30f, -1e30f, -1e30f, -1e30f};
#pragma unroll
  for (int n = 0; n < 4; ++n)
#pragma unroll
    for (int j = 0; j < 4; ++j) {
      float v = s[n][j] * SCALE_;
      s[n][j] = v;
      mx[j] = fmaxf(mx[j], v);
    }
  for (int d = 1; d < 16; d <<= 1) {
#pragma unroll
    for (int j = 0; j < 4; ++j) mx[j] = fmaxf(mx[j], __shfl_xor(mx[j], d));
  }
  float rs[4] = {};
#pragma unroll
  for (int n = 0; n < 4; ++n)
#pragma unroll
    for (int j = 0; j < 4; ++j) {
      float p = __expf(s[n][j] - mx[j]);
      s[n][j] = p;
      rs[j] += p;
    }
  for (int d = 1; d < 16; d <<= 1) {
#pragma unroll
    for (int j = 0; j < 4; ++j) rs[j] += __shfl_xor(rs[j], d);
  }

#pragma unroll
  for (int n = 0; n < 4; ++n)
#pragma unroll
    for (int j = 0; j < 4; ++j)
      Pls[w][fg * 4 + j][n * 16 + fr] = f2bf(s[n][j]);
  __syncthreads();

  f32x4 of[4] = {};
#pragma unroll
  for (int kk = 0; kk < 2; ++kk) {
    u16x8 pf = *(const u16x8*)&Pls[w][fr][kk * 32 + fg * 8];
#pragma unroll
    for (int n = 0; n < 4; ++n) {
      u16x8 qd = *(const u16x8*)&Qdl[n * 16 + fr][kk * 32 + fg * 8];
      of[n] = mfma16(pf, qd, of[n]);
    }
  }

#pragma unroll
  for (int n = 0; n < 4; ++n)
#pragma unroll
    for (int j = 0; j < 4; ++j) {
      int orow = n0 + w * 16 + fg * 4 + j;
      if (orow < NN)
        AO[(size_t)(b * NN + orow) * CC + h * DD + n * 16 + fr] = f2bf(of[n][j] / rs[j]);
    }
}

// ---------------- launch ----------------
extern "C" void kernel_launch(void* const* d_in, const int* in_sizes, int n_in,
                              void* d_out, int out_size, void* d_ws, size_t ws_size,
                              hipStream_t stream) {
  const float* X     = (const float*)d_in[0];
  const float* Wqkv  = (const float*)d_in[1];
  const float* Wproj = (const float*)d_in[2];
  const float* bproj = (const float*)d_in[3];

  char* ws = (char*)d_ws;
  u16* Xb  = (u16*)(ws + 0);            // 18464*1024*2 = 37,814,272
  u16* Wqb = (u16*)(ws + 37814272);     // 3072*1024*2  =  6,291,456
  u16* Wpb = (u16*)(ws + 44105728);     // 1024*1024*2  =  2,097,152
  u16* qkv = (u16*)(ws + 46202880);     // 18464*3072*2 = 113,442,816
  u16* Qpb = (u16*)(ws + 159645696);    // 32*64*1024*2 =  4,194,304
  u16* QdT = (u16*)(ws + 163840000);    // 512*64*64*2  =  4,194,304
  u16* AO  = (u16*)(ws + 168034304);    // 18464*1024*2 = 37,814,272

  cvt_kernel<<<2048, 256, 0, stream>>>(X, Xb, (BB * NN * CC) / 4);
  cvt_kernel<<<1024, 256, 0, stream>>>(Wqkv, Wqb, (3 * CC * CC) / 4);
  cvt_kernel<<<512, 256, 0, stream>>>(Wproj, Wpb, (CC * CC) / 4);

  gemm_bt2<<<145 * 24, 256, 0, stream>>>(Xb, Wqb, qkv, nullptr, nullptr,
                                         MM, 3 * CC, CC, 145, 24);

  pool_kernel<<<BB * 64, 256, 0, stream>>>(qkv, Qpb);
  stage1_kernel<<<BB * HH, 256, 0, stream>>>(qkv, Qpb, QdT);
  stage2_kernel<<<BB * HH * 10, 256, 0, stream>>>(qkv, Qpb, QdT, AO);

  gemm_bt2<<<145 * 8, 256, 0, stream>>>(AO, Wpb, nullptr, (float*)d_out, bproj,
                                        MM, CC, CC, 145, 8);
}